// Round 1
// baseline (294.573 us; speedup 1.0000x reference)
//
#include <hip/hip_runtime.h>
#include <hip/hip_bf16.h>
#include <cstdint>

typedef unsigned short u16;
typedef __attribute__((ext_vector_type(8))) short s16x8;
typedef __attribute__((ext_vector_type(4))) float f32x4;
typedef __attribute__((ext_vector_type(4))) unsigned short u16x4;

#define MFMA16(a, b, c) __builtin_amdgcn_mfma_f32_16x16x32_bf16((a), (b), (c), 0, 0, 0)

__device__ __forceinline__ u16 f2bf(float f) {
  union { float f; uint32_t u; } x; x.f = f;
  uint32_t u = x.u;
  return (u16)((u + 0x7fffu + ((u >> 16) & 1u)) >> 16);
}

__device__ __forceinline__ void gll16(const void* gsrc, void* ldst) {
  __builtin_amdgcn_global_load_lds(
      (const __attribute__((address_space(1))) uint32_t*)(uintptr_t)gsrc,
      (__attribute__((address_space(3))) uint32_t*)(uintptr_t)ldst, 16, 0, 0);
}

// ---------------- f32 -> bf16 conversion ----------------
__global__ __launch_bounds__(256) void cvt_f32_bf16_kernel(
    const f32x4* __restrict__ src, u16x4* __restrict__ dst, int n4) {
  int i = blockIdx.x * 256 + threadIdx.x;
  if (i >= n4) return;
  f32x4 v = src[i];
  u16x4 o;
  #pragma unroll
  for (int j = 0; j < 4; ++j) o[j] = f2bf(v[j]);
  dst[i] = o;
}

// ---------------- fused QKV projection GEMM ----------------
// C[m,n] = sum_k X[m,k] * W[n,k] + bias[n]; M=4096, N=1024, K=1024
// z=0 -> Q out [B,H,S,D]; z=1 -> K out [B,H,S,D]; z=2 -> V out transposed [B,H,D,S]
__global__ __launch_bounds__(256) void proj_qkv_kernel(
    const u16* __restrict__ Xq, const u16* __restrict__ Xk, const u16* __restrict__ Xv,
    const u16* __restrict__ Wq, const u16* __restrict__ Wk, const u16* __restrict__ Wv,
    const float* __restrict__ bq, const float* __restrict__ bk, const float* __restrict__ bv,
    u16* __restrict__ Qo, u16* __restrict__ Ko, u16* __restrict__ Vo) {
  __shared__ __align__(16) u16 Asm[128 * 64];
  __shared__ __align__(16) u16 Bsm[128 * 64];

  const int z = blockIdx.z;
  const u16* X = (z == 0) ? Xq : (z == 1) ? Xk : Xv;
  const u16* W = (z == 0) ? Wq : (z == 1) ? Wk : Wv;
  const float* bias = (z == 0) ? bq : (z == 1) ? bk : bv;

  const int t = threadIdx.x;
  const int lane = t & 63;
  const int l15 = lane & 15, lg = lane >> 4;
  const int wid = t >> 6;
  const int wr = wid >> 1, wc = wid & 1;
  const int m0 = blockIdx.x * 128, n0 = blockIdx.y * 128;

  f32x4 acc[4][4] = {};

  for (int kt = 0; kt < 16; ++kt) {
    __syncthreads();
    #pragma unroll
    for (int i = 0; i < 4; ++i) {
      int tt = i * 256 + t;
      int row = tt >> 3;
      int sg = (tt & 7) ^ (row & 7);
      gll16(X + (size_t)(m0 + row) * 1024 + kt * 64 + sg * 8, Asm + tt * 8);
    }
    #pragma unroll
    for (int i = 0; i < 4; ++i) {
      int tt = i * 256 + t;
      int row = tt >> 3;
      int sg = (tt & 7) ^ (row & 7);
      gll16(W + (size_t)(n0 + row) * 1024 + kt * 64 + sg * 8, Bsm + tt * 8);
    }
    __syncthreads();
    #pragma unroll
    for (int kk = 0; kk < 2; ++kk) {
      s16x8 af[4], bf[4];
      #pragma unroll
      for (int mi = 0; mi < 4; ++mi) {
        int row = wr * 64 + mi * 16 + l15;
        int g = (lg + 4 * kk) ^ (row & 7);
        af[mi] = *(const s16x8*)(Asm + row * 64 + g * 8);
      }
      #pragma unroll
      for (int ni = 0; ni < 4; ++ni) {
        int row = wc * 64 + ni * 16 + l15;
        int g = (lg + 4 * kk) ^ (row & 7);
        bf[ni] = *(const s16x8*)(Bsm + row * 64 + g * 8);
      }
      #pragma unroll
      for (int mi = 0; mi < 4; ++mi)
        #pragma unroll
        for (int ni = 0; ni < 4; ++ni)
          acc[mi][ni] = MFMA16(af[mi], bf[ni], acc[mi][ni]);
    }
  }

  #pragma unroll
  for (int ni = 0; ni < 4; ++ni) {
    const int col = n0 + wc * 64 + ni * 16 + l15;
    const int h = col >> 6, d = col & 63;
    const float bval = bias[col];
    #pragma unroll
    for (int mi = 0; mi < 4; ++mi) {
      const int row0 = m0 + wr * 64 + mi * 16 + lg * 4;
      const int bb = row0 >> 11, s0 = row0 & 2047;
      if (z == 2) {
        u16x4 pk;
        #pragma unroll
        for (int r = 0; r < 4; ++r) pk[r] = f2bf(acc[mi][ni][r] + bval);
        *(u16x4*)(Vo + ((size_t)(bb * 16 + h) * 64 + d) * 2048 + s0) = pk;
      } else {
        u16* dst = (z == 0) ? Qo : Ko;
        #pragma unroll
        for (int r = 0; r < 4; ++r)
          dst[((size_t)(bb * 16 + h) * 2048 + (s0 + r)) * 64 + d] =
              f2bf(acc[mi][ni][r] + bval);
      }
    }
  }
}

// ---------------- flash attention ----------------
// logits = (Q.K^T + position_bias) * 0.125 + mask ; online softmax ; O = P.V
// Q,K: [B,H,S,D] bf16 ; Vt: [B,H,D,S] bf16 ; Out: [B,S,H*D] bf16
__global__ __launch_bounds__(256) void attn_kernel(
    const u16* __restrict__ Qw, const u16* __restrict__ Kw, const u16* __restrict__ Vtw,
    const float* __restrict__ pb, const float* __restrict__ mk, u16* __restrict__ Out) {
  __shared__ __align__(16) u16 Ksm[64 * 64];
  __shared__ __align__(16) u16 Vsm[64 * 64];
  __shared__ __align__(16) u16 Psm[4 * 16 * 72];

  const int qt = blockIdx.x;  // 0..31
  const int h = blockIdx.y;   // 0..15
  const int b = blockIdx.z;   // 0..1
  const int t = threadIdx.x;
  const int lane = t & 63;
  const int wid = t >> 6;
  const int l15 = lane & 15, lg = lane >> 4;
  const size_t bh = (size_t)b * 16 + h;

  // Q A-fragments (held in registers across all kv tiles)
  const int qrow_a = qt * 64 + wid * 16 + l15;
  const u16* qptr = Qw + (bh * 2048 + (size_t)qrow_a) * 64 + lg * 8;
  const s16x8 qf0 = *(const s16x8*)(qptr);
  const s16x8 qf1 = *(const s16x8*)(qptr + 32);

  const int qrow_c = qt * 64 + wid * 16 + lg * 4;  // C-layout base q row
  const float* pb_base = pb + ((size_t)h * 2048 + qrow_c) * 2048;
  const float* mk_base = mk + ((size_t)b * 2048 + qrow_c) * 2048;

  f32x4 oacc[4] = {};
  float m_r[4], l_r[4];
  #pragma unroll
  for (int r = 0; r < 4; ++r) { m_r[r] = -3.0e38f; l_r[r] = 0.f; }

  const u16* kbase = Kw + bh * 2048 * 64;
  const u16* vbase = Vtw + bh * 64 * 2048;

  for (int kt = 0; kt < 32; ++kt) {
    const int kv0 = kt * 64;
    __syncthreads();
    #pragma unroll
    for (int i = 0; i < 2; ++i) {
      int tt = i * 256 + t;
      int row = tt >> 3;
      int sg = (tt & 7) ^ (row & 7);
      gll16(kbase + (size_t)(kv0 + row) * 64 + sg * 8, Ksm + tt * 8);
    }
    #pragma unroll
    for (int i = 0; i < 2; ++i) {
      int tt = i * 256 + t;
      int row = tt >> 3;
      int sg = (tt & 7) ^ (row & 7);
      gll16(vbase + (size_t)row * 2048 + kv0 + sg * 8, Vsm + tt * 8);
    }
    __syncthreads();

    // S = Q.K^T  (rows q, cols kv)
    f32x4 sf[4] = {};
    #pragma unroll
    for (int kk = 0; kk < 2; ++kk) {
      s16x8 q = kk ? qf1 : qf0;
      #pragma unroll
      for (int f = 0; f < 4; ++f) {
        int row = f * 16 + l15;
        int g = (lg + 4 * kk) ^ (row & 7);
        s16x8 kf = *(const s16x8*)(Ksm + row * 64 + g * 8);
        sf[f] = MFMA16(q, kf, sf[f]);
      }
    }

    // logits = (s + pb) * 0.125 + mask ; track tile row-max
    float pmax[4];
    #pragma unroll
    for (int r = 0; r < 4; ++r) pmax[r] = -3.0e38f;
    #pragma unroll
    for (int f = 0; f < 4; ++f) {
      int cc = kv0 + f * 16 + l15;
      #pragma unroll
      for (int r = 0; r < 4; ++r) {
        float lv = (sf[f][r] + pb_base[(size_t)r * 2048 + cc]) * 0.125f +
                   mk_base[(size_t)r * 2048 + cc];
        sf[f][r] = lv;
        pmax[r] = fmaxf(pmax[r], lv);
      }
    }
    #pragma unroll
    for (int off = 1; off < 16; off <<= 1) {
      #pragma unroll
      for (int r = 0; r < 4; ++r) pmax[r] = fmaxf(pmax[r], __shfl_xor(pmax[r], off));
    }
    float corr[4], rsum[4];
    #pragma unroll
    for (int r = 0; r < 4; ++r) {
      float mn = fmaxf(m_r[r], pmax[r]);
      corr[r] = exp2f((m_r[r] - mn) * 1.4426950408889634f);
      m_r[r] = mn;
      rsum[r] = 0.f;
    }
    #pragma unroll
    for (int f = 0; f < 4; ++f) {
      #pragma unroll
      for (int r = 0; r < 4; ++r) {
        float p = exp2f((sf[f][r] - m_r[r]) * 1.4426950408889634f);
        sf[f][r] = p;
        rsum[r] += p;
      }
    }
    #pragma unroll
    for (int off = 1; off < 16; off <<= 1) {
      #pragma unroll
      for (int r = 0; r < 4; ++r) rsum[r] += __shfl_xor(rsum[r], off);
    }
    #pragma unroll
    for (int r = 0; r < 4; ++r) l_r[r] = l_r[r] * corr[r] + rsum[r];
    #pragma unroll
    for (int f = 0; f < 4; ++f) {
      #pragma unroll
      for (int r = 0; r < 4; ++r) oacc[f][r] *= corr[r];
    }

    // P -> bf16 -> per-wave LDS (C-layout write, A-frag read), stride 72 elems
    u16* pw = Psm + wid * (16 * 72);
    #pragma unroll
    for (int f = 0; f < 4; ++f) {
      #pragma unroll
      for (int r = 0; r < 4; ++r)
        pw[(lg * 4 + r) * 72 + f * 16 + l15] = f2bf(sf[f][r]);
    }

    // O += P.V  (V from transposed-layout tile, k-contiguous)
    #pragma unroll
    for (int kk = 0; kk < 2; ++kk) {
      s16x8 pf = *(const s16x8*)(pw + l15 * 72 + kk * 32 + lg * 8);
      #pragma unroll
      for (int f = 0; f < 4; ++f) {
        int row = f * 16 + l15;
        int g = (lg + 4 * kk) ^ (row & 7);
        s16x8 vf = *(const s16x8*)(Vsm + row * 64 + g * 8);
        oacc[f] = MFMA16(pf, vf, oacc[f]);
      }
    }
  }

  #pragma unroll
  for (int r = 0; r < 4; ++r) l_r[r] = 1.f / l_r[r];
  #pragma unroll
  for (int f = 0; f < 4; ++f) {
    #pragma unroll
    for (int r = 0; r < 4; ++r) {
      int q = qrow_c + r;
      Out[((size_t)b * 2048 + q) * 1024 + h * 64 + f * 16 + l15] =
          f2bf(oacc[f][r] * l_r[r]);
    }
  }
}

// ---------------- output projection GEMM ----------------
// out[m,n] = sum_k A[m,k] * Wo[n,k] + bo[n]  (f32 output)
__global__ __launch_bounds__(256) void oproj_kernel(
    const u16* __restrict__ A, const u16* __restrict__ W,
    const float* __restrict__ bias, float* __restrict__ out) {
  __shared__ __align__(16) u16 Asm[128 * 64];
  __shared__ __align__(16) u16 Bsm[128 * 64];

  const int t = threadIdx.x;
  const int lane = t & 63;
  const int l15 = lane & 15, lg = lane >> 4;
  const int wid = t >> 6;
  const int wr = wid >> 1, wc = wid & 1;
  const int m0 = blockIdx.x * 128, n0 = blockIdx.y * 128;

  f32x4 acc[4][4] = {};

  for (int kt = 0; kt < 16; ++kt) {
    __syncthreads();
    #pragma unroll
    for (int i = 0; i < 4; ++i) {
      int tt = i * 256 + t;
      int row = tt >> 3;
      int sg = (tt & 7) ^ (row & 7);
      gll16(A + (size_t)(m0 + row) * 1024 + kt * 64 + sg * 8, Asm + tt * 8);
    }
    #pragma unroll
    for (int i = 0; i < 4; ++i) {
      int tt = i * 256 + t;
      int row = tt >> 3;
      int sg = (tt & 7) ^ (row & 7);
      gll16(W + (size_t)(n0 + row) * 1024 + kt * 64 + sg * 8, Bsm + tt * 8);
    }
    __syncthreads();
    #pragma unroll
    for (int kk = 0; kk < 2; ++kk) {
      s16x8 af[4], bf[4];
      #pragma unroll
      for (int mi = 0; mi < 4; ++mi) {
        int row = wr * 64 + mi * 16 + l15;
        int g = (lg + 4 * kk) ^ (row & 7);
        af[mi] = *(const s16x8*)(Asm + row * 64 + g * 8);
      }
      #pragma unroll
      for (int ni = 0; ni < 4; ++ni) {
        int row = wc * 64 + ni * 16 + l15;
        int g = (lg + 4 * kk) ^ (row & 7);
        bf[ni] = *(const s16x8*)(Bsm + row * 64 + g * 8);
      }
      #pragma unroll
      for (int mi = 0; mi < 4; ++mi)
        #pragma unroll
        for (int ni = 0; ni < 4; ++ni)
          acc[mi][ni] = MFMA16(af[mi], bf[ni], acc[mi][ni]);
    }
  }

  #pragma unroll
  for (int ni = 0; ni < 4; ++ni) {
    const int col = n0 + wc * 64 + ni * 16 + l15;
    const float bval = bias[col];
    #pragma unroll
    for (int mi = 0; mi < 4; ++mi) {
      const int row0 = m0 + wr * 64 + mi * 16 + lg * 4;
      #pragma unroll
      for (int r = 0; r < 4; ++r)
        out[(size_t)(row0 + r) * 1024 + col] = acc[mi][ni][r] + bval;
    }
  }
}

extern "C" void kernel_launch(void* const* d_in, const int* in_sizes, int n_in,
                              void* d_out, int out_size, void* d_ws, size_t ws_size,
                              hipStream_t stream) {
  const float* query = (const float*)d_in[0];
  const float* key_i = (const float*)d_in[1];
  const float* value = (const float*)d_in[2];
  const float* mask  = (const float*)d_in[3];
  const float* pbias = (const float*)d_in[4];
  const float* wq = (const float*)d_in[5];
  const float* bq = (const float*)d_in[6];
  const float* wk = (const float*)d_in[7];
  const float* bk = (const float*)d_in[8];
  const float* wv = (const float*)d_in[9];
  const float* bv = (const float*)d_in[10];
  const float* wo = (const float*)d_in[11];
  const float* bo = (const float*)d_in[12];
  float* out = (float*)d_out;

  uint8_t* ws = (uint8_t*)d_ws;
  u16* Xq = (u16*)(ws + 0);          // 4096x1024 bf16
  u16* Xk = (u16*)(ws + 8388608);
  u16* Xv = (u16*)(ws + 16777216);
  u16* Wq = (u16*)(ws + 25165824);   // 1024x1024 bf16 each
  u16* Wk = (u16*)(ws + 27262976);
  u16* Wv = (u16*)(ws + 29360128);
  u16* Wo = (u16*)(ws + 31457280);
  u16* Qw = (u16*)(ws + 33554432);   // [B,H,S,D] bf16
  u16* Kw = (u16*)(ws + 41943040);   // [B,H,S,D]
  u16* Vt = (u16*)(ws + 50331648);   // [B,H,D,S]
  u16* Aw = (u16*)(ws + 58720256);   // [B,S,H*D]

  cvt_f32_bf16_kernel<<<4096, 256, 0, stream>>>((const f32x4*)query, (u16x4*)Xq, 1048576);
  cvt_f32_bf16_kernel<<<4096, 256, 0, stream>>>((const f32x4*)key_i, (u16x4*)Xk, 1048576);
  cvt_f32_bf16_kernel<<<4096, 256, 0, stream>>>((const f32x4*)value, (u16x4*)Xv, 1048576);
  cvt_f32_bf16_kernel<<<1024, 256, 0, stream>>>((const f32x4*)wq, (u16x4*)Wq, 262144);
  cvt_f32_bf16_kernel<<<1024, 256, 0, stream>>>((const f32x4*)wk, (u16x4*)Wk, 262144);
  cvt_f32_bf16_kernel<<<1024, 256, 0, stream>>>((const f32x4*)wv, (u16x4*)Wv, 262144);
  cvt_f32_bf16_kernel<<<1024, 256, 0, stream>>>((const f32x4*)wo, (u16x4*)Wo, 262144);

  proj_qkv_kernel<<<dim3(32, 8, 3), 256, 0, stream>>>(Xq, Xk, Xv, Wq, Wk, Wv,
                                                      bq, bk, bv, Qw, Kw, Vt);
  attn_kernel<<<dim3(32, 16, 2), 256, 0, stream>>>(Qw, Kw, Vt, pbias, mask, Aw);
  oproj_kernel<<<dim3(32, 8), 256, 0, stream>>>(Aw, Wo, bo, out);
}

// Round 2
// 253.261 us; speedup vs baseline: 1.1631x; 1.1631x over previous
//
#include <hip/hip_runtime.h>
#include <hip/hip_bf16.h>
#include <cstdint>

typedef unsigned short u16;
typedef __attribute__((ext_vector_type(8))) short s16x8;
typedef __attribute__((ext_vector_type(4))) float f32x4;
typedef __attribute__((ext_vector_type(4))) unsigned short u16x4;

#define MFMA16(a, b, c) __builtin_amdgcn_mfma_f32_16x16x32_bf16((a), (b), (c), 0, 0, 0)

__device__ __forceinline__ u16 f2bf(float f) {
  union { float f; uint32_t u; } x; x.f = f;
  uint32_t u = x.u;
  return (u16)((u + 0x7fffu + ((u >> 16) & 1u)) >> 16);
}

__device__ __forceinline__ void gll16(const void* gsrc, void* ldst) {
  __builtin_amdgcn_global_load_lds(
      (const __attribute__((address_space(1))) uint32_t*)(uintptr_t)gsrc,
      (__attribute__((address_space(3))) uint32_t*)(uintptr_t)ldst, 16, 0, 0);
}

// ---------------- fused f32 -> bf16 conversion (one launch for all 7 tensors)
// Destinations are contiguous in ws: Xq,Xk,Xv (1048576 f32x4 each), Wq,Wk,Wv,Wo
// (262144 f32x4 each). Region selection is block-uniform (1024 blocks/chunk).
__global__ __launch_bounds__(256) void cvt_all_kernel(
    const f32x4* __restrict__ q, const f32x4* __restrict__ k, const f32x4* __restrict__ v,
    const f32x4* __restrict__ wq, const f32x4* __restrict__ wk,
    const f32x4* __restrict__ wv, const f32x4* __restrict__ wo,
    u16x4* __restrict__ dst) {
  int i = blockIdx.x * 256 + threadIdx.x;  // 0 .. 4194303
  int r = i >> 18;                         // 262144-element chunks
  const f32x4* src;
  int off;
  if (r < 4)       { src = q;  off = 0; }
  else if (r < 8)  { src = k;  off = 1048576; }
  else if (r < 12) { src = v;  off = 2097152; }
  else if (r == 12){ src = wq; off = 3145728; }
  else if (r == 13){ src = wk; off = 3407872; }
  else if (r == 14){ src = wv; off = 3670016; }
  else             { src = wo; off = 3932160; }
  f32x4 val = src[i - off];
  u16x4 o;
  #pragma unroll
  for (int j = 0; j < 4; ++j) o[j] = f2bf(val[j]);
  dst[i] = o;
}

// ---------------- fused QKV projection GEMM ----------------
// C[m,n] = sum_k X[m,k] * W[n,k] + bias[n]; M=4096, N=1024, K=1024
// z=0 -> Q out [B,H,S,D]; z=1 -> K out [B,H,S,D]; z=2 -> V out transposed [B,H,D,S]
__global__ __launch_bounds__(256) void proj_qkv_kernel(
    const u16* __restrict__ Xq, const u16* __restrict__ Xk, const u16* __restrict__ Xv,
    const u16* __restrict__ Wq, const u16* __restrict__ Wk, const u16* __restrict__ Wv,
    const float* __restrict__ bq, const float* __restrict__ bk, const float* __restrict__ bv,
    u16* __restrict__ Qo, u16* __restrict__ Ko, u16* __restrict__ Vo) {
  __shared__ __align__(16) u16 Asm[128 * 64];
  __shared__ __align__(16) u16 Bsm[128 * 64];

  const int z = blockIdx.z;
  const u16* X = (z == 0) ? Xq : (z == 1) ? Xk : Xv;
  const u16* W = (z == 0) ? Wq : (z == 1) ? Wk : Wv;
  const float* bias = (z == 0) ? bq : (z == 1) ? bk : bv;

  const int t = threadIdx.x;
  const int lane = t & 63;
  const int l15 = lane & 15, lg = lane >> 4;
  const int wid = t >> 6;
  const int wr = wid >> 1, wc = wid & 1;
  const int m0 = blockIdx.x * 128, n0 = blockIdx.y * 128;

  f32x4 acc[4][4] = {};

  for (int kt = 0; kt < 16; ++kt) {
    __syncthreads();
    #pragma unroll
    for (int i = 0; i < 4; ++i) {
      int tt = i * 256 + t;
      int row = tt >> 3;
      int sg = (tt & 7) ^ (row & 7);
      gll16(X + (size_t)(m0 + row) * 1024 + kt * 64 + sg * 8, Asm + tt * 8);
    }
    #pragma unroll
    for (int i = 0; i < 4; ++i) {
      int tt = i * 256 + t;
      int row = tt >> 3;
      int sg = (tt & 7) ^ (row & 7);
      gll16(W + (size_t)(n0 + row) * 1024 + kt * 64 + sg * 8, Bsm + tt * 8);
    }
    __syncthreads();
    #pragma unroll
    for (int kk = 0; kk < 2; ++kk) {
      s16x8 af[4], bf[4];
      #pragma unroll
      for (int mi = 0; mi < 4; ++mi) {
        int row = wr * 64 + mi * 16 + l15;
        int g = (lg + 4 * kk) ^ (row & 7);
        af[mi] = *(const s16x8*)(Asm + row * 64 + g * 8);
      }
      #pragma unroll
      for (int ni = 0; ni < 4; ++ni) {
        int row = wc * 64 + ni * 16 + l15;
        int g = (lg + 4 * kk) ^ (row & 7);
        bf[ni] = *(const s16x8*)(Bsm + row * 64 + g * 8);
      }
      #pragma unroll
      for (int mi = 0; mi < 4; ++mi)
        #pragma unroll
        for (int ni = 0; ni < 4; ++ni)
          acc[mi][ni] = MFMA16(af[mi], bf[ni], acc[mi][ni]);
    }
  }

  #pragma unroll
  for (int ni = 0; ni < 4; ++ni) {
    const int col = n0 + wc * 64 + ni * 16 + l15;
    const int h = col >> 6, d = col & 63;
    const float bval = bias[col];
    #pragma unroll
    for (int mi = 0; mi < 4; ++mi) {
      const int row0 = m0 + wr * 64 + mi * 16 + lg * 4;
      const int bb = row0 >> 11, s0 = row0 & 2047;
      if (z == 2) {
        u16x4 pk;
        #pragma unroll
        for (int r = 0; r < 4; ++r) pk[r] = f2bf(acc[mi][ni][r] + bval);
        *(u16x4*)(Vo + ((size_t)(bb * 16 + h) * 64 + d) * 2048 + s0) = pk;
      } else {
        u16* dst = (z == 0) ? Qo : Ko;
        #pragma unroll
        for (int r = 0; r < 4; ++r)
          dst[((size_t)(bb * 16 + h) * 2048 + (s0 + r)) * 64 + d] =
              f2bf(acc[mi][ni][r] + bval);
      }
    }
  }
}

// ---------------- flash attention, both batches per block ----------------
// logits = (Q.K^T + position_bias) * 0.125 + mask ; online softmax ; O = P.V
// Q,K: [B,H,S,D] bf16 ; Vt: [B,H,D,S] bf16 ; Out: [B,S,H*D] bf16
// pb depends only on (h,q,k) -> load once per tile, feed both batches.
__global__ __launch_bounds__(256) void attn_kernel(
    const u16* __restrict__ Qw, const u16* __restrict__ Kw, const u16* __restrict__ Vtw,
    const float* __restrict__ pb, const float* __restrict__ mk, u16* __restrict__ Out) {
  __shared__ __align__(16) u16 Ksm[2][64 * 64];
  __shared__ __align__(16) u16 Vsm[2][64 * 64];
  __shared__ __align__(16) u16 Psm[2][4][16 * 72];

  const int qt = blockIdx.x;  // 0..31
  const int h = blockIdx.y;   // 0..15
  const int t = threadIdx.x;
  const int lane = t & 63;
  const int wid = t >> 6;
  const int l15 = lane & 15, lg = lane >> 4;

  // Q A-fragments for both batches (kept in registers across all kv tiles)
  const int qrow_a = qt * 64 + wid * 16 + l15;
  s16x8 qf[2][2];
  #pragma unroll
  for (int b = 0; b < 2; ++b) {
    const u16* qptr = Qw + (((size_t)b * 16 + h) * 2048 + qrow_a) * 64 + lg * 8;
    qf[b][0] = *(const s16x8*)(qptr);
    qf[b][1] = *(const s16x8*)(qptr + 32);
  }

  const int qrow_c = qt * 64 + wid * 16 + lg * 4;  // C-layout base q row
  const float* pb_base = pb + ((size_t)h * 2048 + qrow_c) * 2048;

  f32x4 oacc[2][4] = {};
  float m_r[2][4], l_r[2][4];
  #pragma unroll
  for (int b = 0; b < 2; ++b)
    #pragma unroll
    for (int r = 0; r < 4; ++r) { m_r[b][r] = -3.0e38f; l_r[b][r] = 0.f; }

  for (int kt = 0; kt < 32; ++kt) {
    const int kv0 = kt * 64;

    // prefetch pb for this tile into registers BEFORE the staging barrier,
    // so HBM latency hides under global_load_lds staging
    float pbv[4][4];
    #pragma unroll
    for (int f = 0; f < 4; ++f)
      #pragma unroll
      for (int r = 0; r < 4; ++r)
        pbv[f][r] = pb_base[(size_t)r * 2048 + kv0 + f * 16 + l15];

    __syncthreads();
    #pragma unroll
    for (int b = 0; b < 2; ++b) {
      const u16* kbase = Kw + (((size_t)b * 16 + h) * 2048) * 64;
      const u16* vbase = Vtw + (((size_t)b * 16 + h) * 64) * 2048;
      #pragma unroll
      for (int i = 0; i < 2; ++i) {
        int tt = i * 256 + t;
        int row = tt >> 3;
        int sg = (tt & 7) ^ (row & 7);
        gll16(kbase + (size_t)(kv0 + row) * 64 + sg * 8, Ksm[b] + tt * 8);
        gll16(vbase + (size_t)row * 2048 + kv0 + sg * 8, Vsm[b] + tt * 8);
      }
    }
    __syncthreads();

    #pragma unroll
    for (int b = 0; b < 2; ++b) {
      const float* mk_base = mk + ((size_t)b * 2048 + qrow_c) * 2048 + kv0;

      // S = Q.K^T  (rows q, cols kv)
      f32x4 sf[4] = {};
      #pragma unroll
      for (int kk = 0; kk < 2; ++kk) {
        #pragma unroll
        for (int f = 0; f < 4; ++f) {
          int row = f * 16 + l15;
          int g = (lg + 4 * kk) ^ (row & 7);
          s16x8 kf = *(const s16x8*)(Ksm[b] + row * 64 + g * 8);
          sf[f] = MFMA16(qf[b][kk], kf, sf[f]);
        }
      }

      // logits = (s + pb) * 0.125 + mask ; tile row-max
      float pmax[4];
      #pragma unroll
      for (int r = 0; r < 4; ++r) pmax[r] = -3.0e38f;
      #pragma unroll
      for (int f = 0; f < 4; ++f) {
        #pragma unroll
        for (int r = 0; r < 4; ++r) {
          float lv = (sf[f][r] + pbv[f][r]) * 0.125f +
                     mk_base[(size_t)r * 2048 + f * 16 + l15];
          sf[f][r] = lv;
          pmax[r] = fmaxf(pmax[r], lv);
        }
      }
      #pragma unroll
      for (int off = 1; off < 16; off <<= 1) {
        #pragma unroll
        for (int r = 0; r < 4; ++r) pmax[r] = fmaxf(pmax[r], __shfl_xor(pmax[r], off));
      }
      float corr[4], rsum[4];
      #pragma unroll
      for (int r = 0; r < 4; ++r) {
        float mn = fmaxf(m_r[b][r], pmax[r]);
        corr[r] = exp2f((m_r[b][r] - mn) * 1.4426950408889634f);
        m_r[b][r] = mn;
        rsum[r] = 0.f;
      }
      #pragma unroll
      for (int f = 0; f < 4; ++f) {
        #pragma unroll
        for (int r = 0; r < 4; ++r) {
          float p = exp2f((sf[f][r] - m_r[b][r]) * 1.4426950408889634f);
          sf[f][r] = p;
          rsum[r] += p;
        }
      }
      #pragma unroll
      for (int off = 1; off < 16; off <<= 1) {
        #pragma unroll
        for (int r = 0; r < 4; ++r) rsum[r] += __shfl_xor(rsum[r], off);
      }
      #pragma unroll
      for (int r = 0; r < 4; ++r) l_r[b][r] = l_r[b][r] * corr[r] + rsum[r];
      #pragma unroll
      for (int f = 0; f < 4; ++f) {
        #pragma unroll
        for (int r = 0; r < 4; ++r) oacc[b][f][r] *= corr[r];
      }

      // P -> bf16 -> per-wave LDS (C-layout write, A-frag read), stride 72
      u16* pw = &Psm[b][wid][0];
      #pragma unroll
      for (int f = 0; f < 4; ++f) {
        #pragma unroll
        for (int r = 0; r < 4; ++r)
          pw[(lg * 4 + r) * 72 + f * 16 + l15] = f2bf(sf[f][r]);
      }

      // O += P.V  (V from transposed-layout tile, k-contiguous)
      #pragma unroll
      for (int kk = 0; kk < 2; ++kk) {
        s16x8 pf = *(const s16x8*)(pw + l15 * 72 + kk * 32 + lg * 8);
        #pragma unroll
        for (int f = 0; f < 4; ++f) {
          int row = f * 16 + l15;
          int g = (lg + 4 * kk) ^ (row & 7);
          s16x8 vf = *(const s16x8*)(Vsm[b] + row * 64 + g * 8);
          oacc[b][f] = MFMA16(pf, vf, oacc[b][f]);
        }
      }
    }
  }

  #pragma unroll
  for (int b = 0; b < 2; ++b) {
    #pragma unroll
    for (int r = 0; r < 4; ++r) {
      float inv = 1.f / l_r[b][r];
      #pragma unroll
      for (int f = 0; f < 4; ++f) {
        int q = qrow_c + r;
        Out[(((size_t)b * 2048) + q) * 1024 + h * 64 + f * 16 + l15] =
            f2bf(oacc[b][f][r] * inv);
      }
    }
  }
}

// ---------------- output projection GEMM ----------------
// out[m,n] = sum_k A[m,k] * Wo[n,k] + bo[n]  (f32 output)
__global__ __launch_bounds__(256) void oproj_kernel(
    const u16* __restrict__ A, const u16* __restrict__ W,
    const float* __restrict__ bias, float* __restrict__ out) {
  __shared__ __align__(16) u16 Asm[128 * 64];
  __shared__ __align__(16) u16 Bsm[128 * 64];

  const int t = threadIdx.x;
  const int lane = t & 63;
  const int l15 = lane & 15, lg = lane >> 4;
  const int wid = t >> 6;
  const int wr = wid >> 1, wc = wid & 1;
  const int m0 = blockIdx.x * 128, n0 = blockIdx.y * 128;

  f32x4 acc[4][4] = {};

  for (int kt = 0; kt < 16; ++kt) {
    __syncthreads();
    #pragma unroll
    for (int i = 0; i < 4; ++i) {
      int tt = i * 256 + t;
      int row = tt >> 3;
      int sg = (tt & 7) ^ (row & 7);
      gll16(A + (size_t)(m0 + row) * 1024 + kt * 64 + sg * 8, Asm + tt * 8);
    }
    #pragma unroll
    for (int i = 0; i < 4; ++i) {
      int tt = i * 256 + t;
      int row = tt >> 3;
      int sg = (tt & 7) ^ (row & 7);
      gll16(W + (size_t)(n0 + row) * 1024 + kt * 64 + sg * 8, Bsm + tt * 8);
    }
    __syncthreads();
    #pragma unroll
    for (int kk = 0; kk < 2; ++kk) {
      s16x8 af[4], bf[4];
      #pragma unroll
      for (int mi = 0; mi < 4; ++mi) {
        int row = wr * 64 + mi * 16 + l15;
        int g = (lg + 4 * kk) ^ (row & 7);
        af[mi] = *(const s16x8*)(Asm + row * 64 + g * 8);
      }
      #pragma unroll
      for (int ni = 0; ni < 4; ++ni) {
        int row = wc * 64 + ni * 16 + l15;
        int g = (lg + 4 * kk) ^ (row & 7);
        bf[ni] = *(const s16x8*)(Bsm + row * 64 + g * 8);
      }
      #pragma unroll
      for (int mi = 0; mi < 4; ++mi)
        #pragma unroll
        for (int ni = 0; ni < 4; ++ni)
          acc[mi][ni] = MFMA16(af[mi], bf[ni], acc[mi][ni]);
    }
  }

  #pragma unroll
  for (int ni = 0; ni < 4; ++ni) {
    const int col = n0 + wc * 64 + ni * 16 + l15;
    const float bval = bias[col];
    #pragma unroll
    for (int mi = 0; mi < 4; ++mi) {
      const int row0 = m0 + wr * 64 + mi * 16 + lg * 4;
      #pragma unroll
      for (int r = 0; r < 4; ++r)
        out[(size_t)(row0 + r) * 1024 + col] = acc[mi][ni][r] + bval;
    }
  }
}

extern "C" void kernel_launch(void* const* d_in, const int* in_sizes, int n_in,
                              void* d_out, int out_size, void* d_ws, size_t ws_size,
                              hipStream_t stream) {
  const float* query = (const float*)d_in[0];
  const float* key_i = (const float*)d_in[1];
  const float* value = (const float*)d_in[2];
  const float* mask  = (const float*)d_in[3];
  const float* pbias = (const float*)d_in[4];
  const float* wq = (const float*)d_in[5];
  const float* bq = (const float*)d_in[6];
  const float* wk = (const float*)d_in[7];
  const float* bk = (const float*)d_in[8];
  const float* wv = (const float*)d_in[9];
  const float* bv = (const float*)d_in[10];
  const float* wo = (const float*)d_in[11];
  const float* bo = (const float*)d_in[12];
  float* out = (float*)d_out;

  uint8_t* ws = (uint8_t*)d_ws;
  u16* Xq = (u16*)(ws + 0);          // 4096x1024 bf16
  u16* Xk = (u16*)(ws + 8388608);
  u16* Xv = (u16*)(ws + 16777216);
  u16* Wq = (u16*)(ws + 25165824);   // 1024x1024 bf16 each
  u16* Wk = (u16*)(ws + 27262976);
  u16* Wv = (u16*)(ws + 29360128);
  u16* Wo = (u16*)(ws + 31457280);
  u16* Qw = (u16*)(ws + 33554432);   // [B,H,S,D] bf16
  u16* Kw = (u16*)(ws + 41943040);   // [B,H,S,D]
  u16* Vt = (u16*)(ws + 50331648);   // [B,H,D,S]
  u16* Aw = (u16*)(ws + 58720256);   // [B,S,H*D]

  cvt_all_kernel<<<16384, 256, 0, stream>>>(
      (const f32x4*)query, (const f32x4*)key_i, (const f32x4*)value,
      (const f32x4*)wq, (const f32x4*)wk, (const f32x4*)wv, (const f32x4*)wo,
      (u16x4*)Xq);

  proj_qkv_kernel<<<dim3(32, 8, 3), 256, 0, stream>>>(Xq, Xk, Xv, Wq, Wk, Wv,
                                                      bq, bk, bv, Qw, Kw, Vt);
  attn_kernel<<<dim3(32, 16), 256, 0, stream>>>(Qw, Kw, Vt, pbias, mask, Aw);
  oproj_kernel<<<dim3(32, 8), 256, 0, stream>>>(Aw, Wo, bo, out);
}